// Round 12
// baseline (54.064 us; speedup 1.0000x reference)
//
#include <hip/hip_runtime.h>
#include <math.h>

#define EPS 1e-5f
#define LAYERS 6
#define FDIM 2048
#define NTAB 512

__device__ __forceinline__ float gelu_as(float t) {
    // A&S 7.1.26 erf, branchless: gl = relu(t) - 0.5*|t|*poly*exp(-t^2/2)
    float e  = __expf(-0.5f * t * t);
    float at = fabsf(t);
    float wr = __builtin_amdgcn_rcpf(fmaf(0.23164194f, at, 1.0f));
    float poly = fmaf(fmaf(fmaf(fmaf(1.061405429f, wr, -1.453152027f),
                                wr, 1.421413741f),
                           wr, -0.284496736f),
                      wr, 0.254829592f) * wr;
    return fmaf(-0.5f * at, poly * e, fmaxf(t, 0.f));
}

// tab[l][j] = MLP_acc( hn(theta_j) ), hn = ln1_g * z(theta_j) + ln1_b,
// z on the radius-sqrt(3) circle in the plane z0+z1+z2=0.
// Slot j <-> diamond coordinate d = j*(4/NTAB).
// One table entry per block; 256 threads split the 2048 hidden units.
// (R6/R9-exact shape — verified passing; occupancy > L2-traffic, per R11.)
// Block 0 additionally zeroes cnt[32] (ws is 0xAA-poisoned before timing;
// stream order guarantees the zero lands before fused6's atomics).
__global__ __launch_bounds__(256) void tab_kernel(
        const float* __restrict__ W1, const float* __restrict__ b1,
        const float* __restrict__ W2,
        const float* __restrict__ ln1_g, const float* __restrict__ ln1_b,
        float4* __restrict__ tab, int* __restrict__ cnt) {
    int l = blockIdx.x >> 9;           // NTAB = 512 entries per layer
    int j = blockIdx.x & (NTAB - 1);
    int tid = threadIdx.x;
    int wv = tid >> 6, lane = tid & 63;

    if (blockIdx.x == 0 && tid < 32) cnt[tid] = 0;

    float d = (float)j * (4.0f / NTAB);
    float cn = (d <= 2.0f) ? 1.0f - d : d - 3.0f;
    float asn = 1.0f - fabsf(cn);
    float sn = (d <= 2.0f) ? asn : -asn;
    float inv = 1.0f / sqrtf(cn * cn + sn * sn);
    float c = cn * inv, s = sn * inv;
    float z0 = fmaf(1.2247449f, c, 0.70710678f * s);
    float z1 = fmaf(-1.2247449f, c, 0.70710678f * s);
    float z2 = -1.4142136f * s;
    float hx0 = fmaf(ln1_g[l*3+0], z0, ln1_b[l*3+0]);
    float hx1 = fmaf(ln1_g[l*3+1], z1, ln1_b[l*3+1]);
    float hx2 = fmaf(ln1_g[l*3+2], z2, ln1_b[l*3+2]);

    const float* w1p = W1 + (size_t)l * FDIM * 3;
    const float* b1p = b1 + (size_t)l * FDIM;
    const float* w2p = W2 + (size_t)l * 3 * FDIM;

    float a0 = 0.f, a1 = 0.f, a2 = 0.f;
#pragma unroll
    for (int i = 0; i < 8; ++i) {
        int k = i * 256 + tid;
        float t = fmaf(w1p[k*3+0], hx0,
                  fmaf(w1p[k*3+1], hx1,
                  fmaf(w1p[k*3+2], hx2, b1p[k])));
        float gl = gelu_as(t);
        a0 = fmaf(gl, w2p[k],          a0);
        a1 = fmaf(gl, w2p[FDIM + k],   a1);
        a2 = fmaf(gl, w2p[2*FDIM + k], a2);
    }
#pragma unroll
    for (int m = 1; m < 64; m <<= 1) {
        a0 += __shfl_xor(a0, m);
        a1 += __shfl_xor(a1, m);
        a2 += __shfl_xor(a2, m);
    }
    __shared__ float red[4][3];
    if (lane == 0) { red[wv][0] = a0; red[wv][1] = a1; red[wv][2] = a2; }
    __syncthreads();
    if (tid == 0) {
        tab[(size_t)l * NTAB + j] = make_float4(
            red[0][0] + red[1][0] + red[2][0] + red[3][0],
            red[0][1] + red[1][1] + red[2][1] + red[3][1],
            red[0][2] + red[1][2] + red[2][2] + red[3][2], 0.f);
    }
}

// conv + all 6 layers + head, fused. Block = 128 threads: (s:32) x (half:2) x (n:2).
// Body identical to the R9-verified kernel; instead of storing h, each wave
// computes its 10-element head partial (half-0 lanes contribute), lane 0 stores
// it, and the LAST wave per batch (cnt[b]==31) reduces all 32 partials in fixed
// index order (deterministic) and writes out[b] — no h buffer, no head dispatch.
__global__ __launch_bounds__(128) void fused6_kernel(
        const float* __restrict__ x,
        const float* __restrict__ conv_w, const float* __restrict__ conv_b,
        const float* __restrict__ Wqkv, const float* __restrict__ bqkv,
        const float* __restrict__ Wo,   const float* __restrict__ bo,
        const float* __restrict__ ln1_g, const float* __restrict__ ln1_b,
        const float* __restrict__ b2v,
        const float* __restrict__ ln2_g, const float* __restrict__ ln2_b,
        const float4* __restrict__ tab,
        const float* __restrict__ mlp_W, const float* __restrict__ mlp_b,
        float* __restrict__ partials, int* __restrict__ cnt,
        float* __restrict__ out) {
    int b = blockIdx.x >> 4, npair = blockIdx.x & 15;
    int tid  = threadIdx.x;
    int s    = tid & 31;
    int half = (tid >> 5) & 1;
    int nl   = tid >> 6;            // 0/1 == wave index
    int lane = tid & 63;
    int n = npair * 2 + nl;
    __shared__ float2 kv[2][3][32];

    // in-block conv (each wave computes it redundantly; 64-lane reduce)
    const float4* xb4 = (const float4*)(x + (size_t)b * 3072);
    const float4* cw4 = (const float4*)conv_w;
    float cs0 = 0.f, cs1 = 0.f, cs2 = 0.f;
#pragma unroll
    for (int i = 0; i < 4; ++i) {
        int f0 = i * 64 + lane;
        float4 xv = xb4[f0], wv = cw4[f0];
        cs0 = fmaf(xv.x, wv.x, fmaf(xv.y, wv.y, fmaf(xv.z, wv.z, fmaf(xv.w, wv.w, cs0))));
        float4 xv1 = xb4[f0 + 256], wv1 = cw4[f0 + 256];
        cs1 = fmaf(xv1.x, wv1.x, fmaf(xv1.y, wv1.y, fmaf(xv1.z, wv1.z, fmaf(xv1.w, wv1.w, cs1))));
        float4 xv2 = xb4[f0 + 512], wv2 = cw4[f0 + 512];
        cs2 = fmaf(xv2.x, wv2.x, fmaf(xv2.y, wv2.y, fmaf(xv2.z, wv2.z, fmaf(xv2.w, wv2.w, cs2))));
    }
#pragma unroll
    for (int m = 1; m < 64; m <<= 1) {
        cs0 += __shfl_xor(cs0, m);
        cs1 += __shfl_xor(cs1, m);
        cs2 += __shfl_xor(cs2, m);
    }
    float c0 = cs0 + conv_b[0], c1 = cs1 + conv_b[1], c2 = cs2 + conv_b[2];

    int flat = s * 96 + n * 3;
    const float* xb = x + (size_t)b * 3072 + flat;
    float h0 = xb[0] + ((flat     < 1024) ? c0 : (flat     < 2048 ? c1 : c2));
    float h1 = xb[1] + ((flat + 1 < 1024) ? c0 : (flat + 1 < 2048 ? c1 : c2));
    float h2 = xb[2] + ((flat + 2 < 1024) ? c0 : (flat + 2 < 2048 ? c1 : c2));

    for (int l = 0; l < LAYERS; ++l) {
        const float* wq = Wqkv + l * 27;
        const float* bq = bqkv + l * 9;
        float q[3], kk[3], vv[3];
#pragma unroll
        for (int f = 0; f < 3; ++f) {
            q[f]  = fmaf(wq[f*3+0], h0, fmaf(wq[f*3+1], h1, fmaf(wq[f*3+2], h2, bq[f])));
            kk[f] = fmaf(wq[9+f*3+0], h0, fmaf(wq[9+f*3+1], h1, fmaf(wq[9+f*3+2], h2, bq[3+f])));
            vv[f] = fmaf(wq[18+f*3+0], h0, fmaf(wq[18+f*3+1], h1, fmaf(wq[18+f*3+2], h2, bq[6+f])));
        }
        __syncthreads();   // previous layer's kv reads complete
        if (half == 0) {
#pragma unroll
            for (int e = 0; e < 3; ++e) kv[nl][e][s] = make_float2(kk[e], vv[e]);
        }
        __syncthreads();

        float oatt[3];
#pragma unroll
        for (int e = 0; e < 3; ++e) {
            float a = q[e] * 1.44269504f;   // exp2 base; no max-sub (|q*k| bounded)
            float psum = 0.f, pacc = 0.f;
#pragma unroll
            for (int i = 0; i < 16; ++i) {
                float2 kvt = kv[nl][e][half * 16 + i];
                float p = exp2f(a * kvt.x);
                psum += p;
                pacc = fmaf(p, kvt.y, pacc);
            }
            float sum = psum + __shfl_xor(psum, 32);
            float acc = pacc + __shfl_xor(pacc, 32);
            oatt[e] = acc / sum;
        }
        const float* wo = Wo + l * 9;
        float x0 = h0 + fmaf(wo[0], oatt[0], fmaf(wo[1], oatt[1], fmaf(wo[2], oatt[2], bo[l*3+0])));
        float x1 = h1 + fmaf(wo[3], oatt[0], fmaf(wo[4], oatt[1], fmaf(wo[5], oatt[2], bo[l*3+1])));
        float x2 = h2 + fmaf(wo[6], oatt[0], fmaf(wo[7], oatt[1], fmaf(wo[8], oatt[2], bo[l*3+2])));
        // ln1 -> z (pre-gain), hn (post-gain)
        float mu = (x0 + x1 + x2) * (1.f/3.f);
        float d0 = x0 - mu, d1 = x1 - mu, d2 = x2 - mu;
        float var = (d0*d0 + d1*d1 + d2*d2) * (1.f/3.f);
        float inv = 1.0f / sqrtf(var + EPS);
        float z0 = d0 * inv, z1 = d1 * inv, z2 = d2 * inv;
        float hn0 = fmaf(z0, ln1_g[l*3+0], ln1_b[l*3+0]);
        float hn1 = fmaf(z1, ln1_g[l*3+1], ln1_b[l*3+1]);
        float hn2 = fmaf(z2, ln1_g[l*3+2], ln1_b[l*3+2]);
        // MLP via 1-D manifold table: diamond coordinate of z
        float cc = 0.40824829f * (z0 - z1);
        float ss = 0.23570226f * (z0 + z1 - 2.f * z2);
        float m  = fabsf(cc) + fabsf(ss) + 1e-30f;
        float cnn = cc * __builtin_amdgcn_rcpf(m);
        float dq = (ss >= 0.f) ? (1.f - cnn) : (3.f + cnn);
        float xq = dq * (float)(NTAB / 4);
        float fl = floorf(xq);
        float fr = xq - fl;
        int j0 = ((int)fl) & (NTAB - 1);
        int j1 = (j0 + 1) & (NTAB - 1);
        float4 ta = tab[(size_t)l * NTAB + j0];
        float4 tb = tab[(size_t)l * NTAB + j1];
        float f0 = fmaf(fr, tb.x - ta.x, ta.x);
        float f1 = fmaf(fr, tb.y - ta.y, ta.y);
        float f2 = fmaf(fr, tb.z - ta.z, ta.z);
        // residual + ln2
        float y0 = hn0 + f0 + b2v[l*3+0];
        float y1 = hn1 + f1 + b2v[l*3+1];
        float y2 = hn2 + f2 + b2v[l*3+2];
        float mu2 = (y0 + y1 + y2) * (1.f/3.f);
        float e0 = y0 - mu2, e1 = y1 - mu2, e2 = y2 - mu2;
        float var2 = (e0*e0 + e1*e1 + e2*e2) * (1.f/3.f);
        float inv2 = 1.0f / sqrtf(var2 + EPS);
        h0 = fmaf(e0 * inv2, ln2_g[l*3+0], ln2_b[l*3+0]);
        h1 = fmaf(e1 * inv2, ln2_g[l*3+1], ln2_b[l*3+1]);
        h2 = fmaf(e2 * inv2, ln2_g[l*3+2], ln2_b[l*3+2]);
    }

    // head partial: this wave covers 32 positions (half-0 lanes hold them; the
    // half-1 copies are bit-identical, contribute 0 to avoid double count)
    float p10[10];
#pragma unroll
    for (int j = 0; j < 10; ++j) {
        const float* w = mlp_W + (size_t)j * 3072 + flat;
        p10[j] = (half == 0) ? fmaf(h0, w[0], fmaf(h1, w[1], h2 * w[2])) : 0.f;
    }
#pragma unroll
    for (int m = 1; m < 64; m <<= 1) {
#pragma unroll
        for (int j = 0; j < 10; ++j) p10[j] += __shfl_xor(p10[j], m);
    }
    int widx = npair * 2 + nl;          // 0..31 within batch b
    int old = 0;
    if (lane == 0) {
#pragma unroll
        for (int j = 0; j < 10; ++j) partials[(size_t)(b * 32 + widx) * 10 + j] = p10[j];
        __threadfence();
        old = atomicAdd(&cnt[b], 1);
    }
    old = __shfl(old, 0);
    if (old == 31) {                    // last wave for this batch reduces
        __threadfence();
        if (lane < 10) {
            float sacc = mlp_b[lane];
#pragma unroll
            for (int i = 0; i < 32; ++i)
                sacc += partials[(size_t)(b * 32 + i) * 10 + lane];
            out[b * 10 + lane] = sacc;
        }
    }
}

extern "C" void kernel_launch(void* const* d_in, const int* in_sizes, int n_in,
                              void* d_out, int out_size, void* d_ws, size_t ws_size,
                              hipStream_t stream) {
    const float* x      = (const float*)d_in[0];
    const float* conv_w = (const float*)d_in[1];
    const float* conv_b = (const float*)d_in[2];
    const float* Wqkv   = (const float*)d_in[3];
    const float* bqkv   = (const float*)d_in[4];
    const float* Wo     = (const float*)d_in[5];
    const float* bo     = (const float*)d_in[6];
    const float* W1     = (const float*)d_in[7];
    const float* b1     = (const float*)d_in[8];
    const float* W2     = (const float*)d_in[9];
    const float* b2     = (const float*)d_in[10];
    const float* ln1_g  = (const float*)d_in[11];
    const float* ln1_b  = (const float*)d_in[12];
    const float* ln2_g  = (const float*)d_in[13];
    const float* ln2_b  = (const float*)d_in[14];
    const float* mlp_W  = (const float*)d_in[15];
    const float* mlp_b  = (const float*)d_in[16];
    float* out = (float*)d_out;

    float4* tab      = (float4*)d_ws;                      // 6*NTAB float4 = 49152 B
    float*  partials = (float*)((char*)d_ws + 49152);      // 32*32*10 floats = 40960 B
    int*    cnt      = (int*)((char*)d_ws + 90112);        // 32 ints

    hipLaunchKernelGGL(tab_kernel, dim3(LAYERS * NTAB), dim3(256), 0, stream,
                       W1, b1, W2, ln1_g, ln1_b, tab, cnt);
    hipLaunchKernelGGL(fused6_kernel, dim3(512), dim3(128), 0, stream,
                       x, conv_w, conv_b, Wqkv, bqkv, Wo, bo,
                       ln1_g, ln1_b, b2, ln2_g, ln2_b, tab, mlp_W, mlp_b,
                       partials, cnt, out);
}

// Round 13
// 31.568 us; speedup vs baseline: 1.7126x; 1.7126x over previous
//
#include <hip/hip_runtime.h>
#include <math.h>

#define EPS 1e-5f
#define LAYERS 6
#define FDIM 2048
#define NTAB 512

// h layout: [b][3072] flat, element (s,n,e) at b*3072 + s*96 + n*3 + e

__device__ __forceinline__ float gelu_as(float t) {
    // A&S 7.1.26 erf, branchless: gl = relu(t) - 0.5*|t|*poly*exp(-t^2/2)
    float e  = __expf(-0.5f * t * t);
    float at = fabsf(t);
    float wr = __builtin_amdgcn_rcpf(fmaf(0.23164194f, at, 1.0f));
    float poly = fmaf(fmaf(fmaf(fmaf(1.061405429f, wr, -1.453152027f),
                                wr, 1.421413741f),
                           wr, -0.284496736f),
                      wr, 0.254829592f) * wr;
    return fmaf(-0.5f * at, poly * e, fmaxf(t, 0.f));
}

// tab[l][j] = MLP_acc( hn(theta_j) ), hn = ln1_g * z(theta_j) + ln1_b.
// One table entry per block; 256 threads split the 2048 hidden units.
// (R9-exact — verified passing.)
__global__ __launch_bounds__(256) void tab_kernel(
        const float* __restrict__ W1, const float* __restrict__ b1,
        const float* __restrict__ W2,
        const float* __restrict__ ln1_g, const float* __restrict__ ln1_b,
        float4* __restrict__ tab) {
    int l = blockIdx.x >> 9;           // NTAB = 512 entries per layer
    int j = blockIdx.x & (NTAB - 1);
    int tid = threadIdx.x;
    int wv = tid >> 6, lane = tid & 63;

    float d = (float)j * (4.0f / NTAB);
    float cn = (d <= 2.0f) ? 1.0f - d : d - 3.0f;
    float asn = 1.0f - fabsf(cn);
    float sn = (d <= 2.0f) ? asn : -asn;
    float inv = 1.0f / sqrtf(cn * cn + sn * sn);
    float c = cn * inv, s = sn * inv;
    float z0 = fmaf(1.2247449f, c, 0.70710678f * s);
    float z1 = fmaf(-1.2247449f, c, 0.70710678f * s);
    float z2 = -1.4142136f * s;
    float hx0 = fmaf(ln1_g[l*3+0], z0, ln1_b[l*3+0]);
    float hx1 = fmaf(ln1_g[l*3+1], z1, ln1_b[l*3+1]);
    float hx2 = fmaf(ln1_g[l*3+2], z2, ln1_b[l*3+2]);

    const float* w1p = W1 + (size_t)l * FDIM * 3;
    const float* b1p = b1 + (size_t)l * FDIM;
    const float* w2p = W2 + (size_t)l * 3 * FDIM;

    float a0 = 0.f, a1 = 0.f, a2 = 0.f;
#pragma unroll
    for (int i = 0; i < 8; ++i) {
        int k = i * 256 + tid;
        float t = fmaf(w1p[k*3+0], hx0,
                  fmaf(w1p[k*3+1], hx1,
                  fmaf(w1p[k*3+2], hx2, b1p[k])));
        float gl = gelu_as(t);
        a0 = fmaf(gl, w2p[k],          a0);
        a1 = fmaf(gl, w2p[FDIM + k],   a1);
        a2 = fmaf(gl, w2p[2*FDIM + k], a2);
    }
#pragma unroll
    for (int m = 1; m < 64; m <<= 1) {
        a0 += __shfl_xor(a0, m);
        a1 += __shfl_xor(a1, m);
        a2 += __shfl_xor(a2, m);
    }
    __shared__ float red[4][3];
    if (lane == 0) { red[wv][0] = a0; red[wv][1] = a1; red[wv][2] = a2; }
    __syncthreads();
    if (tid == 0) {
        tab[(size_t)l * NTAB + j] = make_float4(
            red[0][0] + red[1][0] + red[2][0] + red[3][0],
            red[0][1] + red[1][1] + red[2][1] + red[3][1],
            red[0][2] + red[1][2] + red[2][2] + red[3][2], 0.f);
    }
}

// conv + all 6 layers fused. Block = 256 threads: (s:32) x (sub:4) x (n:2).
// Each position (b,n,s) is carried by FOUR threads (sub 0..3) that duplicate
// the cheap scalar tail identically; the 32-term softmax loop is split across
// the subs (8 exp2 each), combined by shfl_xor(32) (sub bit0, intra-wave) and
// a symmetric LDS exchange across the wave pair (sub bit1).
// kv tiles per (n,s); sub==0 writes. All 4 copies compute identical h.
__global__ __launch_bounds__(256) void fused6_kernel(
        const float* __restrict__ x,
        const float* __restrict__ conv_w, const float* __restrict__ conv_b,
        const float* __restrict__ Wqkv, const float* __restrict__ bqkv,
        const float* __restrict__ Wo,   const float* __restrict__ bo,
        const float* __restrict__ ln1_g, const float* __restrict__ ln1_b,
        const float* __restrict__ b2v,
        const float* __restrict__ ln2_g, const float* __restrict__ ln2_b,
        const float4* __restrict__ tab,
        float* __restrict__ h) {
    int b = blockIdx.x >> 4, npair = blockIdx.x & 15;
    int tid   = threadIdx.x;
    int s     = tid & 31;
    int sub   = (tid >> 5) & 3;
    int subhi = (tid >> 6) & 1;
    int nl    = tid >> 7;           // 0/1
    int lane  = tid & 63;
    int n = npair * 2 + nl;
    __shared__ float2 kv[2][3][32];
    __shared__ float red[2][2][32][6];   // [nl][subhi][s][psum0..2,pacc0..2]

    // in-block conv (each wave computes it redundantly; 64-lane reduce)
    const float4* xb4 = (const float4*)(x + (size_t)b * 3072);
    const float4* cw4 = (const float4*)conv_w;
    float cs0 = 0.f, cs1 = 0.f, cs2 = 0.f;
#pragma unroll
    for (int i = 0; i < 4; ++i) {
        int f0 = i * 64 + lane;
        float4 xv = xb4[f0], wv = cw4[f0];
        cs0 = fmaf(xv.x, wv.x, fmaf(xv.y, wv.y, fmaf(xv.z, wv.z, fmaf(xv.w, wv.w, cs0))));
        float4 xv1 = xb4[f0 + 256], wv1 = cw4[f0 + 256];
        cs1 = fmaf(xv1.x, wv1.x, fmaf(xv1.y, wv1.y, fmaf(xv1.z, wv1.z, fmaf(xv1.w, wv1.w, cs1))));
        float4 xv2 = xb4[f0 + 512], wv2 = cw4[f0 + 512];
        cs2 = fmaf(xv2.x, wv2.x, fmaf(xv2.y, wv2.y, fmaf(xv2.z, wv2.z, fmaf(xv2.w, wv2.w, cs2))));
    }
#pragma unroll
    for (int m = 1; m < 64; m <<= 1) {
        cs0 += __shfl_xor(cs0, m);
        cs1 += __shfl_xor(cs1, m);
        cs2 += __shfl_xor(cs2, m);
    }
    float c0 = cs0 + conv_b[0], c1 = cs1 + conv_b[1], c2 = cs2 + conv_b[2];

    int flat = s * 96 + n * 3;
    const float* xb = x + (size_t)b * 3072 + flat;
    float h0 = xb[0] + ((flat     < 1024) ? c0 : (flat     < 2048 ? c1 : c2));
    float h1 = xb[1] + ((flat + 1 < 1024) ? c0 : (flat + 1 < 2048 ? c1 : c2));
    float h2 = xb[2] + ((flat + 2 < 1024) ? c0 : (flat + 2 < 2048 ? c1 : c2));

    for (int l = 0; l < LAYERS; ++l) {
        const float* wq = Wqkv + l * 27;
        const float* bq = bqkv + l * 9;
        float q[3], kk[3], vv[3];
#pragma unroll
        for (int f = 0; f < 3; ++f) {
            q[f]  = fmaf(wq[f*3+0], h0, fmaf(wq[f*3+1], h1, fmaf(wq[f*3+2], h2, bq[f])));
            kk[f] = fmaf(wq[9+f*3+0], h0, fmaf(wq[9+f*3+1], h1, fmaf(wq[9+f*3+2], h2, bq[3+f])));
            vv[f] = fmaf(wq[18+f*3+0], h0, fmaf(wq[18+f*3+1], h1, fmaf(wq[18+f*3+2], h2, bq[6+f])));
        }
        __syncthreads();   // prev layer's kv/red reads complete
        if (sub == 0) {
#pragma unroll
            for (int e = 0; e < 3; ++e) kv[nl][e][s] = make_float2(kk[e], vv[e]);
        }
        __syncthreads();

        float psum[3], pacc[3];
#pragma unroll
        for (int e = 0; e < 3; ++e) {
            float a = q[e] * 1.44269504f;   // exp2 base; no max-sub (|q*k| bounded)
            psum[e] = 0.f; pacc[e] = 0.f;
#pragma unroll
            for (int i = 0; i < 8; ++i) {
                float2 kvt = kv[nl][e][sub * 8 + i];
                float p = exp2f(a * kvt.x);
                psum[e] += p;
                pacc[e] = fmaf(p, kvt.y, pacc[e]);
            }
            psum[e] += __shfl_xor(psum[e], 32);   // combine sub bit0
            pacc[e] += __shfl_xor(pacc[e], 32);
        }
        if (!(sub & 1)) {
#pragma unroll
            for (int e = 0; e < 3; ++e) {
                red[nl][subhi][s][e]     = psum[e];
                red[nl][subhi][s][3 + e] = pacc[e];
            }
        }
        __syncthreads();

        float oatt[3];
#pragma unroll
        for (int e = 0; e < 3; ++e) {
            float sum = red[nl][0][s][e]     + red[nl][1][s][e];
            float acc = red[nl][0][s][3 + e] + red[nl][1][s][3 + e];
            oatt[e] = acc / sum;
        }
        const float* wo = Wo + l * 9;
        float x0 = h0 + fmaf(wo[0], oatt[0], fmaf(wo[1], oatt[1], fmaf(wo[2], oatt[2], bo[l*3+0])));
        float x1 = h1 + fmaf(wo[3], oatt[0], fmaf(wo[4], oatt[1], fmaf(wo[5], oatt[2], bo[l*3+1])));
        float x2 = h2 + fmaf(wo[6], oatt[0], fmaf(wo[7], oatt[1], fmaf(wo[8], oatt[2], bo[l*3+2])));
        // ln1 -> z (pre-gain), hn (post-gain)
        float mu = (x0 + x1 + x2) * (1.f/3.f);
        float d0 = x0 - mu, d1 = x1 - mu, d2 = x2 - mu;
        float var = (d0*d0 + d1*d1 + d2*d2) * (1.f/3.f);
        float inv = 1.0f / sqrtf(var + EPS);
        float z0 = d0 * inv, z1 = d1 * inv, z2 = d2 * inv;
        float hn0 = fmaf(z0, ln1_g[l*3+0], ln1_b[l*3+0]);
        float hn1 = fmaf(z1, ln1_g[l*3+1], ln1_b[l*3+1]);
        float hn2 = fmaf(z2, ln1_g[l*3+2], ln1_b[l*3+2]);
        // MLP via 1-D manifold table: diamond coordinate of z
        float cc = 0.40824829f * (z0 - z1);
        float ss = 0.23570226f * (z0 + z1 - 2.f * z2);
        float m  = fabsf(cc) + fabsf(ss) + 1e-30f;
        float cnn = cc * __builtin_amdgcn_rcpf(m);
        float dq = (ss >= 0.f) ? (1.f - cnn) : (3.f + cnn);
        float xq = dq * (float)(NTAB / 4);
        float fl = floorf(xq);
        float fr = xq - fl;
        int j0 = ((int)fl) & (NTAB - 1);
        int j1 = (j0 + 1) & (NTAB - 1);
        float4 ta = tab[(size_t)l * NTAB + j0];
        float4 tb = tab[(size_t)l * NTAB + j1];
        float f0 = fmaf(fr, tb.x - ta.x, ta.x);
        float f1 = fmaf(fr, tb.y - ta.y, ta.y);
        float f2 = fmaf(fr, tb.z - ta.z, ta.z);
        // residual + ln2
        float y0 = hn0 + f0 + b2v[l*3+0];
        float y1 = hn1 + f1 + b2v[l*3+1];
        float y2 = hn2 + f2 + b2v[l*3+2];
        float mu2 = (y0 + y1 + y2) * (1.f/3.f);
        float e0 = y0 - mu2, e1 = y1 - mu2, e2 = y2 - mu2;
        float var2 = (e0*e0 + e1*e1 + e2*e2) * (1.f/3.f);
        float inv2 = 1.0f / sqrtf(var2 + EPS);
        h0 = fmaf(e0 * inv2, ln2_g[l*3+0], ln2_b[l*3+0]);
        h1 = fmaf(e1 * inv2, ln2_g[l*3+1], ln2_b[l*3+1]);
        h2 = fmaf(e2 * inv2, ln2_g[l*3+2], ln2_b[l*3+2]);
    }
    if (sub == 0) {
        float* hp = h + (size_t)b * 3072 + flat;
        hp[0] = h0; hp[1] = h1; hp[2] = h2;
    }
}

__global__ void head_kernel(const float* __restrict__ h,
                            const float* __restrict__ mlp_W,
                            const float* __restrict__ mlp_b,
                            float* __restrict__ out) {
    int b = blockIdx.x, tid = threadIdx.x;
    float hh[12];
#pragma unroll
    for (int m = 0; m < 12; ++m) hh[m] = h[(size_t)b * 3072 + tid + m * 256];
    float p[10];
#pragma unroll
    for (int j = 0; j < 10; ++j) {
        const float* wj = mlp_W + (size_t)j * 3072;
        float s = 0.f;
#pragma unroll
        for (int m = 0; m < 12; ++m) s = fmaf(hh[m], wj[tid + m * 256], s);
#pragma unroll
        for (int d = 32; d >= 1; d >>= 1) s += __shfl_down(s, d);
        p[j] = s;
    }
    __shared__ float red[10][4];
    int wave = tid >> 6, lane = tid & 63;
    if (lane == 0) {
#pragma unroll
        for (int j = 0; j < 10; ++j) red[j][wave] = p[j];
    }
    __syncthreads();
    if (tid < 10)
        out[b * 10 + tid] = red[tid][0] + red[tid][1] + red[tid][2] + red[tid][3] + mlp_b[tid];
}

extern "C" void kernel_launch(void* const* d_in, const int* in_sizes, int n_in,
                              void* d_out, int out_size, void* d_ws, size_t ws_size,
                              hipStream_t stream) {
    const float* x      = (const float*)d_in[0];
    const float* conv_w = (const float*)d_in[1];
    const float* conv_b = (const float*)d_in[2];
    const float* Wqkv   = (const float*)d_in[3];
    const float* bqkv   = (const float*)d_in[4];
    const float* Wo     = (const float*)d_in[5];
    const float* bo     = (const float*)d_in[6];
    const float* W1     = (const float*)d_in[7];
    const float* b1     = (const float*)d_in[8];
    const float* W2     = (const float*)d_in[9];
    const float* b2     = (const float*)d_in[10];
    const float* ln1_g  = (const float*)d_in[11];
    const float* ln1_b  = (const float*)d_in[12];
    const float* ln2_g  = (const float*)d_in[13];
    const float* ln2_b  = (const float*)d_in[14];
    const float* mlp_W  = (const float*)d_in[15];
    const float* mlp_b  = (const float*)d_in[16];
    float* out = (float*)d_out;

    float*  h   = (float*)d_ws;                        // 98304 floats (393216 B)
    float4* tab = (float4*)((char*)d_ws + 393216);     // 6*NTAB float4

    hipLaunchKernelGGL(tab_kernel, dim3(LAYERS * NTAB), dim3(256), 0, stream,
                       W1, b1, W2, ln1_g, ln1_b, tab);
    hipLaunchKernelGGL(fused6_kernel, dim3(512), dim3(256), 0, stream,
                       x, conv_w, conv_b, Wqkv, bqkv, Wo, bo,
                       ln1_g, ln1_b, b2, ln2_g, ln2_b, tab, h);
    hipLaunchKernelGGL(head_kernel, dim3(32), dim3(256), 0, stream, h, mlp_W, mlp_b, out);
}